// Round 11
// baseline (141.675 us; speedup 1.0000x reference)
//
#include <hip/hip_runtime.h>

// SSIM loss, R13. R12 post-mortem: 43 us, occupancy 46% (plan worked) but
// REGRESSED vs R11 ~39 -> occupancy wasn't binding; LDS pipe is (~84KB/blk-iter
// round-trip, ~17-20us/CU + 8us conflicts; staging writes were the conflict
// source). R13: DELETE X staging entirely.
//  - h-conv A-frag = 8 contiguous px of one row -> load DIRECTLY from global
//    (2 float4/img/lane, guarded), build 4 plane frags (a,b,a2+b2,ab) in regs.
//    No X planes in LDS. Col-overlap (1.6x) between waves is L1/L2-served.
//  - LDS = Ht transpose only (wave-own cols: each wave writes AND reads only
//    cols [16w,16w+16)) -> ZERO barriers in the main loop; waves decoupled.
//  - TH=32 (R12 lesson: halo economics beat occupancy), HTP=56 (2-way banks),
//    LDS 28.9KB -> 5 blocks/CU, __launch_bounds__(256,5).
//  - persistent 1280 blocks, bc = bc0 + 10*it (4-5 iters; no barriers ->
//    uneven iter counts safe).
// Retained: one-k-step band MFMA (bh=g[kl-l15-3], bv=g[kl-l15]), LDS g-table,
// rs compensation, SSIM on D2 fragments, hierarchical reduction.

typedef __attribute__((ext_vector_type(2))) float  f32x2;
typedef __attribute__((ext_vector_type(4))) float  f32x4;
typedef __fp16 f16;
typedef __attribute__((ext_vector_type(2))) __fp16 h2v;
typedef __attribute__((ext_vector_type(4))) __fp16 h4;
typedef __attribute__((ext_vector_type(8))) __fp16 h8;

constexpr int IMG_H = 512;
constexpr int IMG_W = 512;
constexpr int PL    = IMG_H * IMG_W;
constexpr int NBC   = 48;
constexpr int TW    = 64;
constexpr int TH    = 32;
constexpr int NPERS = 1280;                // 5 blocks/CU x 256 CU
// tiles = 8 x 16 x 48 = 6144; bc0 = bid>>7 in [0,10); bc += 10 per iter

constexpr int HTP   = 56;                  // Ht pitch (halves): 28 dw stride, 2-way
constexpr int HTQS  = 64 * HTP;            // 3584 halves per plane
constexpr int SMEMH = 4 * HTQS;            // 14336 halves = 28,672 B

constexpr float C1 = 1.0e-4f;
constexpr float C2 = 9.0e-4f;

// Normalized gaussian g[d] = exp(-(d-5)^2/4.5)/sum, f32-rounded.
__device__ const float GW[11] = {
    0.00102838f, 0.00759876f, 0.03600077f, 0.10936070f, 0.21300553f,
    0.26601172f, 0.21300553f, 0.10936070f, 0.03600077f, 0.00759876f,
    0.00102838f};

__device__ __forceinline__ h8 ldfrag(const f16* __restrict__ gtab, int base) {
    h8 b;
#pragma unroll
    for (int i = 0; i < 8; ++i) b[i] = gtab[base + i];
    return b;
}

__global__ __launch_bounds__(64) void ssim_init(double* acc) {
    if (threadIdx.x == 0) acc[0] = 0.0;
}

__global__ __launch_bounds__(256, 5) void ssim_main(const float* __restrict__ sr,
                                                    const float* __restrict__ hr,
                                                    double* __restrict__ sink,
                                                    int mode) {
    __shared__ __align__(16) f16 smem[SMEMH];   // Ht[4][64 cols][56]
    __shared__ __align__(8)  f16 gtab[128];     // zero-padded weights, g at [66..76]
    __shared__ float wsums[4];

    const int tid  = threadIdx.x;
    const int w    = tid >> 6;
    const int lane = tid & 63;
    const int l15  = lane & 15;
    const int grp8 = (lane >> 4) << 3;
    const int grp4 = (lane >> 4) << 2;

    const int bx  = blockIdx.x & 7;
    const int by  = (blockIdx.x >> 3) & 15;
    const int bc0 = blockIdx.x >> 7;            // 0..9
    const int gr0 = by * TH - 5;
    const int gc0 = bx * TW - 8;

    // loop-invariant per-lane load geometry: row rb+16*Mt, cols colh..colh+7
    const int colh = gc0 + 16 * w + grp8;       // multiple of 8
    const bool cok = (unsigned)colh < (unsigned)IMG_W;
    const int rb   = gr0 + l15;

    // ---- g-table fill ----
    if (tid < 128) {
        const int d = tid - 66;
        float v = 0.f;
        if ((unsigned)d <= 10u) v = GW[d];
        gtab[tid] = (f16)v;
    }

    // ---- rs compensation (pure-constant f16 round-trip; == gtab values) ----
    float s16 = 0.f;
#pragma unroll
    for (int d = 0; d <= 10; ++d) s16 += (float)(f16)GW[d];
    const float rs = 1.0f / (s16 * s16);

    __syncthreads();                            // gtab ready (only barrier before end)

    const h8 bh = ldfrag(gtab, 63 + grp8 - l15);   // h-conv: g[kl-l15-3]
    const h8 bv = ldfrag(gtab, 66 + grp8 - l15);   // v-conv: g[kl-l15]

    float local = 0.f;

    for (int bc = bc0; bc < NBC; bc += 10) {
        const float* __restrict__ srp = sr + (size_t)bc * PL;
        const float* __restrict__ hrp = hr + (size_t)bc * PL;

        // ---- h-conv: A-frags direct from global; 4 planes x 3 M-tiles ----
        f32x4 acc[4][3] = {};                   // [plane a,b,s,p][Mt]
#pragma unroll
        for (int Mt = 0; Mt < 3; ++Mt) {
            const int r  = rb + 16 * Mt;
            const bool ok = cok & ((unsigned)r < (unsigned)IMG_H);
            float4 a0, a1, b0, b1;
            a0 = a1 = b0 = b1 = (float4){0.f, 0.f, 0.f, 0.f};
            if (ok) {
                const float4* pa = (const float4*)&srp[r * IMG_W + colh];
                const float4* pb = (const float4*)&hrp[r * IMG_W + colh];
                a0 = pa[0]; a1 = pa[1];
                b0 = pb[0]; b1 = pb[1];
            }
            const f32x2* A0 = (const f32x2*)&a0;
            const f32x2* A1 = (const f32x2*)&a1;
            const f32x2* B0 = (const f32x2*)&b0;
            const f32x2* B1 = (const f32x2*)&b1;
            const f32x2 s0 = A0[0] * A0[0] + B0[0] * B0[0];
            const f32x2 s1 = A0[1] * A0[1] + B0[1] * B0[1];
            const f32x2 s2 = A1[0] * A1[0] + B1[0] * B1[0];
            const f32x2 s3 = A1[1] * A1[1] + B1[1] * B1[1];
            const f32x2 p0 = A0[0] * B0[0], p1 = A0[1] * B0[1];
            const f32x2 p2 = A1[0] * B1[0], p3 = A1[1] * B1[1];
            union { h2v h2[4]; h8 v; } fa, fb, fs, fp;
            fa.h2[0] = __builtin_amdgcn_cvt_pkrtz(A0[0].x, A0[0].y);
            fa.h2[1] = __builtin_amdgcn_cvt_pkrtz(A0[1].x, A0[1].y);
            fa.h2[2] = __builtin_amdgcn_cvt_pkrtz(A1[0].x, A1[0].y);
            fa.h2[3] = __builtin_amdgcn_cvt_pkrtz(A1[1].x, A1[1].y);
            fb.h2[0] = __builtin_amdgcn_cvt_pkrtz(B0[0].x, B0[0].y);
            fb.h2[1] = __builtin_amdgcn_cvt_pkrtz(B0[1].x, B0[1].y);
            fb.h2[2] = __builtin_amdgcn_cvt_pkrtz(B1[0].x, B1[0].y);
            fb.h2[3] = __builtin_amdgcn_cvt_pkrtz(B1[1].x, B1[1].y);
            fs.h2[0] = __builtin_amdgcn_cvt_pkrtz(s0.x, s0.y);
            fs.h2[1] = __builtin_amdgcn_cvt_pkrtz(s1.x, s1.y);
            fs.h2[2] = __builtin_amdgcn_cvt_pkrtz(s2.x, s2.y);
            fs.h2[3] = __builtin_amdgcn_cvt_pkrtz(s3.x, s3.y);
            fp.h2[0] = __builtin_amdgcn_cvt_pkrtz(p0.x, p0.y);
            fp.h2[1] = __builtin_amdgcn_cvt_pkrtz(p1.x, p1.y);
            fp.h2[2] = __builtin_amdgcn_cvt_pkrtz(p2.x, p2.y);
            fp.h2[3] = __builtin_amdgcn_cvt_pkrtz(p3.x, p3.y);
            acc[0][Mt] = __builtin_amdgcn_mfma_f32_16x16x32_f16(fa.v, bh, acc[0][Mt], 0, 0, 0);
            acc[1][Mt] = __builtin_amdgcn_mfma_f32_16x16x32_f16(fb.v, bh, acc[1][Mt], 0, 0, 0);
            acc[2][Mt] = __builtin_amdgcn_mfma_f32_16x16x32_f16(fs.v, bh, acc[2][Mt], 0, 0, 0);
            acc[3][Mt] = __builtin_amdgcn_mfma_f32_16x16x32_f16(fp.v, bh, acc[3][Mt], 0, 0, 0);
        }

        // ---- per plane: transpose-store D1 -> wave-own Ht cols, then v-conv.
        //      Same-wave LDS RAW only (in-order via lgkmcnt); NO barrier. ----
        f32x4 acc2[4][2];
        const int cbase = (16 * w + l15) * HTP;
#pragma unroll
        for (int q = 0; q < 4; ++q) {
#pragma unroll
            for (int Mt = 0; Mt < 3; ++Mt) {
                union { h2v h2[2]; h4 v; } u;
                u.h2[0] = __builtin_amdgcn_cvt_pkrtz(acc[q][Mt][0], acc[q][Mt][1]);
                u.h2[1] = __builtin_amdgcn_cvt_pkrtz(acc[q][Mt][2], acc[q][Mt][3]);
                *(h4*)&smem[q * HTQS + cbase + 16 * Mt + grp4] = u.v;
            }
            const h8 a0 = *(const h8*)&smem[q * HTQS + cbase + grp8];       // j 0..31
            const h8 a1 = *(const h8*)&smem[q * HTQS + cbase + grp8 + 16];  // j 16..47
            const f32x4 z = {0.f, 0.f, 0.f, 0.f};
            acc2[q][0] = __builtin_amdgcn_mfma_f32_16x16x32_f16(a0, bv, z, 0, 0, 0);
            acc2[q][1] = __builtin_amdgcn_mfma_f32_16x16x32_f16(a1, bv, z, 0, 0, 0);
        }

        // ---- SSIM map on D2 (8 px/thread: row=16*nt+l15, col=16w+grp4+e) ----
#pragma unroll
        for (int nt = 0; nt < 2; ++nt) {
            const f32x4 m1 = acc2[0][nt] * rs;
            const f32x4 m2 = acc2[1][nt] * rs;
            const f32x4 S  = acc2[2][nt] * rs;   // E[a^2+b^2]
            const f32x4 pp = acc2[3][nt] * rs;   // E[ab]
            const f32x4 mu1s = m1 * m1, mu2s = m2 * m2, mu12 = m1 * m2;
            const f32x4 sg12 = pp - mu12;
            const f32x4 sgs  = S - mu1s - mu2s;
            const f32x4 num = (2.f * mu12 + C1) * (2.f * sg12 + C2);
            const f32x4 den = (mu1s + mu2s + C1) * (sgs + C2) + 1e-12f;
#pragma unroll
            for (int e = 0; e < 4; ++e)
                local += num[e] * __builtin_amdgcn_rcpf(den[e]);
        }
    }

    // ---- block reduction ----
#pragma unroll
    for (int offr = 32; offr > 0; offr >>= 1)
        local += __shfl_down(local, offr, 64);
    if ((tid & 63) == 0) wsums[tid >> 6] = local;
    __syncthreads();
    if (tid == 0) {
        const double bsum = (double)(wsums[0] + wsums[1] + wsums[2] + wsums[3]);
        if (mode == 0) {
            sink[blockIdx.x] = bsum;
        } else {
            atomicAdd(sink, bsum);
        }
    }
}

__global__ __launch_bounds__(256) void ssim_finalize(const double* __restrict__ partial,
                                                     float* __restrict__ out, int count) {
    __shared__ double ws[4];
    double s = 0.0;
    for (int i = threadIdx.x; i < count; i += 256) s += partial[i];
#pragma unroll
    for (int off = 32; off > 0; off >>= 1)
        s += __shfl_down(s, off, 64);
    const int lane = threadIdx.x & 63, wave = threadIdx.x >> 6;
    if (lane == 0) ws[wave] = s;
    __syncthreads();
    if (threadIdx.x == 0) {
        const double tot = ws[0] + ws[1] + ws[2] + ws[3];
        const double n = (double)NBC * IMG_H * IMG_W;
        out[0] = (float)(1.0 - tot / n);
    }
}

extern "C" void kernel_launch(void* const* d_in, const int* in_sizes, int n_in,
                              void* d_out, int out_size, void* d_ws, size_t ws_size,
                              hipStream_t stream) {
    const float* sr = (const float*)d_in[0];
    const float* hr = (const float*)d_in[1];
    float* out = (float*)d_out;

    if (ws_size >= (size_t)NPERS * sizeof(double)) {
        double* partial = (double*)d_ws; // fully overwritten each call
        ssim_main<<<dim3(NPERS), dim3(256), 0, stream>>>(sr, hr, partial, 0);
        ssim_finalize<<<dim3(1), dim3(256), 0, stream>>>(partial, out, NPERS);
    } else {
        double* acc = (double*)d_ws;
        ssim_init<<<dim3(1), dim3(64), 0, stream>>>(acc);
        ssim_main<<<dim3(NPERS), dim3(256), 0, stream>>>(sr, hr, acc, 1);
        ssim_finalize<<<dim3(1), dim3(256), 0, stream>>>(acc, out, 1);
    }
}